// Round 1
// baseline (1025.745 us; speedup 1.0000x reference)
//
#include <hip/hip_runtime.h>
#include <math.h>

// ---------------------------------------------------------------------------
// Problem dims: B_IN=15, B1=10, B2=6, F1=20, F2=40, F_OUT=10
// M1=19, C1=9, M2=11, C2=5, batch=128
// ---------------------------------------------------------------------------

// workspace layout (offsets in floats; all even -> float2 aligned)
constexpr int OFF_WS2   = 0;                     // W_S2_FWD  [30][10][19]
constexpr int OFF_WINV1 = OFF_WS2   + 5700;      // W_INV1    [20][10][19][19]
constexpr int OFF_WSO3  = OFF_WINV1 + 72200;     // W_SO3_FWD [20][6][11][11]
constexpr int OFF_WINV2 = OFF_WSO3  + 14520;     // W_INV2    [12][6][11][11]
constexpr int OFF_WINT  = OFF_WINV2 + 8712;      // W_INT     [12] (+pad)
constexpr int OFF_FE1   = OFF_WINT  + 16;        // FE1  cplx [19][30]
constexpr int OFF_EA1   = OFF_FE1   + 1140;      // E_A1 cplx [19][20]
constexpr int OFF_FF2   = OFF_EA1   + 760;       // FF2  cplx [11][20]
constexpr int OFF_EA2   = OFF_FF2   + 440;       // E_A2 cplx [11][12]
constexpr int OFF_BS2   = OFF_EA2   + 264;       // B_S2 cplx [24][10][19]
constexpr int OFF_BSO3  = OFF_BS2   + 9120;      // B_SO3 cplx[144][6][11][11]
constexpr int OFF_PSI   = OFF_BSO3  + 209088;    // psi  cplx [20][10][19]
constexpr int OFF_X     = OFF_PSI   + 7600;      // X    cplx [128][10][19]
constexpr int OFF_X2    = OFF_X     + 48640;     // X2   cplx [128][20][6][11][11]
constexpr int OFF_PSI2  = OFF_X2    + 3717120;   // psi2 cplx [20][40][6][11][11]
constexpr int OFF_FEAT  = OFF_PSI2  + 1161600;   // feat      [128][40]
// total = OFF_FEAT + 5120 = 5,262,040 floats  (~21.0 MB)

#define DPI 3.14159265358979323846

// ---------------------------------------------------------------------------
// table-building helpers (double precision, matches numpy reference)
// ---------------------------------------------------------------------------
__device__ __forceinline__ double dfact(int n) {
    double f = 1.0;
    for (int i = 2; i <= n; ++i) f *= (double)i;
    return f;
}
__device__ __forceinline__ double dpowi(double x, int n) {
    double r = 1.0;
    for (int i = 0; i < n; ++i) r *= x;
    return r;
}
__device__ double wig_d(int l, int mi, int ni, double beta) {
    // mi, ni in 0..2l ; m = mi-l, n = ni-l
    int m = mi - l, n = ni - l;
    double cb = cos(0.5 * beta), sb = sin(0.5 * beta);
    double pref = sqrt(dfact(l + m) * dfact(l - m) * dfact(l + n) * dfact(l - n));
    int s0 = (n - m) > 0 ? (n - m) : 0;
    int s1 = (l + n) < (l - m) ? (l + n) : (l - m);
    double v = 0.0;
    for (int s = s0; s <= s1; ++s) {
        double term = dpowi(cb, 2 * l + n - m - 2 * s) * dpowi(sb, m - n + 2 * s) /
                      (dfact(l + n - s) * dfact(s) * dfact(m - n + s) * dfact(l - m - s));
        v += ((m - n + s) & 1) ? -term : term;
    }
    return pref * v;
}
__device__ double wig_pad(int l, int m, int n, int c, double beta) {
    if (m < c - l || m > c + l || n < c - l || n > c + l) return 0.0;
    return wig_d(l, m - (c - l), n - (c - l), beta);
}
__device__ double quad_w(int b, int k) {
    double beta = DPI * (2 * k + 1) / (4.0 * b);
    double s = 0.0;
    for (int j = 0; j < b; ++j) s += sin((2 * j + 1) * beta) / (double)(2 * j + 1);
    return 2.0 / b * sin(beta) * s;
}

// total element ids: 5700+72200+14520+8712+12+570+380+220+132+4560+104544 = 211550
__global__ __launch_bounds__(256) void build_tables_kernel(float* ws) {
    int idx = blockIdx.x * 256 + threadIdx.x;
    // R0: W_S2_FWD [k=30][l=10][m=19]
    if (idx < 5700) {
        int k = idx / 190, r = idx % 190, l = r / 19, m = r % 19;
        double beta = DPI * (2 * k + 1) / 60.0;
        ws[OFF_WS2 + idx] = (float)(quad_w(15, k) * wig_pad(l, m, 9, 9, beta));
        return;
    }
    idx -= 5700;
    // R1: W_INV1 [k=20][l=10][m=19][n=19]
    if (idx < 72200) {
        int k = idx / 3610, r = idx % 3610, l = r / 361, r2 = r % 361, m = r2 / 19, n = r2 % 19;
        double beta = DPI * (2 * k + 1) / 40.0;
        ws[OFF_WINV1 + idx] = (float)((2 * l + 1) * wig_pad(l, m, n, 9, beta));
        return;
    }
    idx -= 72200;
    // R2: W_SO3_FWD [k=20][l=6][m=11][n=11]
    if (idx < 14520) {
        int k = idx / 726, r = idx % 726, l = r / 121, m = (r % 121) / 11, n = r % 11;
        double beta = DPI * (2 * k + 1) / 40.0;
        ws[OFF_WSO3 + idx] = (float)(quad_w(10, k) * wig_pad(l, m, n, 5, beta));
        return;
    }
    idx -= 14520;
    // R3: W_INV2 [k=12][l=6][11][11]
    if (idx < 8712) {
        int k = idx / 726, r = idx % 726, l = r / 121, m = (r % 121) / 11, n = r % 11;
        double beta = DPI * (2 * k + 1) / 24.0;
        ws[OFF_WINV2 + idx] = (float)((2 * l + 1) * wig_pad(l, m, n, 5, beta));
        return;
    }
    idx -= 8712;
    // R4: W_INT [12]
    if (idx < 12) { ws[OFF_WINT + idx] = (float)quad_w(6, idx); return; }
    idx -= 12;
    // R5: FE1 [m=19][t=30]  exp(-2*pi*i*(m-9)*t/30)
    if (idx < 570) {
        int m = idx / 30, t = idx % 30;
        double ang = -2.0 * DPI * (double)((m - 9) * t) / 30.0;
        ws[OFF_FE1 + 2 * idx] = (float)cos(ang);
        ws[OFF_FE1 + 2 * idx + 1] = (float)sin(ang);
        return;
    }
    idx -= 570;
    // R6: E_A1 [m=19][a=20]  exp(+2*pi*i*(m-9)*a/20)
    if (idx < 380) {
        int m = idx / 20, a = idx % 20;
        double ang = 2.0 * DPI * (double)((m - 9) * a) / 20.0;
        ws[OFF_EA1 + 2 * idx] = (float)cos(ang);
        ws[OFF_EA1 + 2 * idx + 1] = (float)sin(ang);
        return;
    }
    idx -= 380;
    // R7: FF2 [mi=11][a=20]  exp(-2*pi*i*(mi-5)*a/20)
    if (idx < 220) {
        int m = idx / 20, a = idx % 20;
        double ang = -2.0 * DPI * (double)((m - 5) * a) / 20.0;
        ws[OFF_FF2 + 2 * idx] = (float)cos(ang);
        ws[OFF_FF2 + 2 * idx + 1] = (float)sin(ang);
        return;
    }
    idx -= 220;
    // R8: E_A2 [m=11][a=12]  exp(+2*pi*i*(m-5)*a/12)
    if (idx < 132) {
        int m = idx / 12, a = idx % 12;
        double ang = 2.0 * DPI * (double)((m - 5) * a) / 12.0;
        ws[OFF_EA2 + 2 * idx] = (float)cos(ang);
        ws[OFF_EA2 + 2 * idx + 1] = (float)sin(ang);
        return;
    }
    idx -= 132;
    // R9: B_S2 [p=24][l=10][m=19]
    if (idx < 4560) {
        int p = idx / 190, r = idx % 190, l = r / 19, m = r % 19;
        int bi = p / 8, ai = p % 8;
        double beta = (bi + 1) * (DPI / 24.0);
        double alpha = 2.0 * DPI * ai / 8.0;
        double re = 0.0, im = 0.0;
        if (m - 9 >= -l && m - 9 <= l) {
            double d = wig_d(l, m - 9 + l, l, beta);
            double ang = -(double)(m - 9) * alpha;
            re = d * cos(ang); im = d * sin(ang);
        }
        ws[OFF_BS2 + 2 * idx] = (float)re;
        ws[OFF_BS2 + 2 * idx + 1] = (float)im;
        return;
    }
    idx -= 4560;
    // R10: B_SO3 [p=144][l=6][m=11][n=11]
    if (idx < 104544) {
        int p = idx / 726, r = idx % 726, l = r / 121, m = (r % 121) / 11, n = r % 11;
        int bi = p / 48, ai = (p % 48) / 6, gi = p % 6;
        double beta = (bi + 1) * (DPI / 24.0);
        double alpha = 2.0 * DPI * ai / 8.0;
        double gamma = 2.0 * DPI * gi / 6.0;
        double re = 0.0, im = 0.0;
        if (m - 5 >= -l && m - 5 <= l && n - 5 >= -l && n - 5 <= l) {
            double d = wig_d(l, m - 5 + l, n - 5 + l, beta);
            double ang = -((double)(m - 5) * alpha + (double)(n - 5) * gamma);
            re = d * cos(ang); im = d * sin(ang);
        }
        ws[OFF_BSO3 + 2 * idx] = (float)re;
        ws[OFF_BSO3 + 2 * idx + 1] = (float)im;
        return;
    }
}

// ---------------------------------------------------------------------------
// psi = kernel1 . B_S2  -> [o=20][l=10][m=19] complex
// ---------------------------------------------------------------------------
__global__ __launch_bounds__(256) void psi1_kernel(float* ws, const float* __restrict__ k1) {
    int idx = blockIdx.x * 256 + threadIdx.x;
    if (idx >= 3800) return;
    int o = idx / 190, r = idx % 190;
    const float2* BS2 = (const float2*)(ws + OFF_BS2);
    float2 s = {0.f, 0.f};
    for (int p = 0; p < 24; ++p) {
        float w = k1[o * 24 + p];
        float2 bv = BS2[p * 190 + r];
        s.x += w * bv.x; s.y += w * bv.y;
    }
    ((float2*)(ws + OFF_PSI))[idx] = s;
}

// ---------------------------------------------------------------------------
// psi2 = kernel2 . B_SO3 -> [i=20][o=40][l=6][m=11][n=11] complex
// ---------------------------------------------------------------------------
__global__ __launch_bounds__(256) void psi2_kernel(float* ws, const float* __restrict__ k2) {
    int idx = blockIdx.x * 256 + threadIdx.x;
    if (idx >= 580800) return;
    int i = idx / 29040, r = idx % 29040, o = r / 726, lmn = r % 726;
    const float2* BS = (const float2*)(ws + OFF_BSO3);
    float2 s = {0.f, 0.f};
    for (int p = 0; p < 144; ++p) {
        float w = k2[(i * 40 + o) * 144 + p];
        float2 bv = BS[p * 726 + lmn];
        s.x += w * bv.x; s.y += w * bv.y;
    }
    ((float2*)(ws + OFF_PSI2))[idx] = s;
}

// ---------------------------------------------------------------------------
// X[b,l,m] = sum_k W_S2_FWD[k,l,m] * (sum_t x[b,k,t] FE1[m,t])
// ---------------------------------------------------------------------------
__global__ __launch_bounds__(256) void xform1_kernel(float* ws, const float* __restrict__ x) {
    const int tid = threadIdx.x, b = blockIdx.x;
    const float2* FE1 = (const float2*)(ws + OFF_FE1);
    const float* WS2 = ws + OFF_WS2;
    float2* Xg = (float2*)(ws + OFF_X) + b * 190;
    __shared__ float xs[900];
    __shared__ float2 xm[570];
    for (int i = tid; i < 900; i += 256) xs[i] = x[b * 900 + i];
    __syncthreads();
    for (int i = tid; i < 570; i += 256) {
        int k = i / 19, m = i % 19;
        float2 s = {0.f, 0.f};
        #pragma unroll
        for (int t = 0; t < 30; ++t) {
            float v = xs[k * 30 + t];
            float2 e = FE1[m * 30 + t];
            s.x += v * e.x; s.y += v * e.y;
        }
        xm[k * 19 + m] = s;
    }
    __syncthreads();
    for (int i = tid; i < 190; i += 256) {
        int l = i / 19, m = i % 19;
        float2 s = {0.f, 0.f};
        for (int k = 0; k < 30; ++k) {
            float w = WS2[k * 190 + l * 19 + m];
            float2 v = xm[k * 19 + m];
            s.x += w * v.x; s.y += w * v.y;
        }
        Xg[i] = s;
    }
}

// ---------------------------------------------------------------------------
// stage1: per (b,o): Z -> fh_k -> y_k -> relu -> fft2(sel) -> X2 accumulate
// ---------------------------------------------------------------------------
__global__ __launch_bounds__(256) void stage1_kernel(float* ws) {
    const int tid = threadIdx.x;
    const int b = blockIdx.x / 20;
    const int o = blockIdx.x % 20;
    const float2* Xg  = (const float2*)(ws + OFF_X) + b * 190;
    const float2* Pg  = (const float2*)(ws + OFF_PSI) + o * 190;
    const float*  WI1 = ws + OFF_WINV1;
    const float*  WS3 = ws + OFF_WSO3;
    const float2* EA1 = (const float2*)(ws + OFF_EA1);
    const float2* FF2 = (const float2*)(ws + OFF_FF2);
    float2* X2g = (float2*)(ws + OFF_X2) + (b * 20 + o) * 726;

    __shared__ float2 Xs[190];
    __shared__ float2 Ps[190];
    __shared__ float2 Zs[3610];
    __shared__ float2 fh[361];
    __shared__ float2 tt[380];
    __shared__ float  yy[400];
    __shared__ float2 uu[220];
    __shared__ float2 ymn[121];
    __shared__ float2 acc2[726];

    for (int i = tid; i < 190; i += 256) { Xs[i] = Xg[i]; Ps[i] = Pg[i]; }
    for (int i = tid; i < 726; i += 256) acc2[i] = make_float2(0.f, 0.f);
    __syncthreads();
    // Z[l,m,n] = X[l,m]*conj(psi[l,n])
    for (int i = tid; i < 3610; i += 256) {
        int l = i / 361, r = i % 361, m = r / 19, n = r % 19;
        float2 a = Xs[l * 19 + m], c = Ps[l * 19 + n];
        Zs[i] = make_float2(a.x * c.x + a.y * c.y, a.y * c.x - a.x * c.y);
    }
    __syncthreads();

    for (int k = 0; k < 20; ++k) {
        // fh[m,n] = sum_l W_INV1[k,l,m,n]*Z[l,m,n]
        for (int i = tid; i < 361; i += 256) {
            float2 s = {0.f, 0.f};
            const float* w = WI1 + k * 3610 + i;
            #pragma unroll
            for (int l = 0; l < 10; ++l) {
                float wv = w[l * 361];
                float2 z = Zs[l * 361 + i];
                s.x += wv * z.x; s.y += wv * z.y;
            }
            fh[i] = s;
        }
        __syncthreads();
        // tt[m,g] = sum_n fh[m,n]*E_G1[n,g]
        for (int i = tid; i < 380; i += 256) {
            int m = i / 20, g = i % 20;
            float2 s = {0.f, 0.f};
            #pragma unroll
            for (int n = 0; n < 19; ++n) {
                float2 f = fh[m * 19 + n], e = EA1[n * 20 + g];
                s.x += f.x * e.x - f.y * e.y;
                s.y += f.x * e.y + f.y * e.x;
            }
            tt[i] = s;
        }
        __syncthreads();
        // yy[a,g] = relu(Re sum_m E_A1[m,a]*tt[m,g])
        for (int i = tid; i < 400; i += 256) {
            int a = i / 20, g = i % 20;
            float s = 0.f;
            #pragma unroll
            for (int m = 0; m < 19; ++m) {
                float2 e = EA1[m * 20 + a], t = tt[m * 20 + g];
                s += e.x * t.x - e.y * t.y;
            }
            yy[i] = s > 0.f ? s : 0.f;
        }
        __syncthreads();
        // uu[mi,g] = sum_a yy[a,g]*FF2[mi,a]
        for (int i = tid; i < 220; i += 256) {
            int mi = i / 20, g = i % 20;
            float2 s = {0.f, 0.f};
            #pragma unroll
            for (int a = 0; a < 20; ++a) {
                float v = yy[a * 20 + g];
                float2 e = FF2[mi * 20 + a];
                s.x += v * e.x; s.y += v * e.y;
            }
            uu[i] = s;
        }
        __syncthreads();
        // ymn[mi,ni] = sum_g uu[mi,g]*FF2[ni,g]
        for (int i = tid; i < 121; i += 256) {
            int mi = i / 11, ni = i % 11;
            float2 s = {0.f, 0.f};
            #pragma unroll
            for (int g = 0; g < 20; ++g) {
                float2 u = uu[mi * 20 + g], e = FF2[ni * 20 + g];
                s.x += u.x * e.x - u.y * e.y;
                s.y += u.x * e.y + u.y * e.x;
            }
            ymn[i] = s;
        }
        __syncthreads();
        // acc2[l2,m,n] += W_SO3_FWD[k,l2,m,n] * ymn[m,n]
        for (int i = tid; i < 726; i += 256) {
            float w = WS3[k * 726 + i];
            float2 v = ymn[i % 121];
            acc2[i].x += w * v.x; acc2[i].y += w * v.y;
        }
        __syncthreads();
    }
    for (int i = tid; i < 726; i += 256) X2g[i] = acc2[i];
}

// ---------------------------------------------------------------------------
// stage2: per (b,o): Z2 -> fh2 -> y2 -> relu -> weighted sum -> feat[b,o]
// ---------------------------------------------------------------------------
__global__ __launch_bounds__(256) void stage2_kernel(float* ws) {
    const int tid = threadIdx.x;
    const int b = blockIdx.x / 40;
    const int o = blockIdx.x % 40;
    const float2* X2g = (const float2*)(ws + OFF_X2) + b * 20 * 726;
    const float2* P2g = (const float2*)(ws + OFF_PSI2);
    const float*  WI2 = ws + OFF_WINV2;
    const float2* EA2 = (const float2*)(ws + OFF_EA2);
    const float*  WIT = ws + OFF_WINT;
    float* featg = ws + OFF_FEAT;

    __shared__ float2 xi[726];
    __shared__ float2 pp[726];
    __shared__ float2 z2[726];
    __shared__ float2 fh2[1452];
    __shared__ float2 t2[1584];
    __shared__ float red[4];

    // each thread owns z2 indices tid, tid+256, tid+512(<726)
    const int i0 = tid, i1 = tid + 256, i2 = tid + 512;
    float2 a0 = {0.f, 0.f}, a1 = {0.f, 0.f}, a2 = {0.f, 0.f};
    int l, r;
    l = i0 / 121; r = i0 % 121;
    const int xo0 = l * 121 + (r / 11) * 11, po0 = l * 121 + (r % 11) * 11;
    l = i1 / 121; r = i1 % 121;
    const int xo1 = l * 121 + (r / 11) * 11, po1 = l * 121 + (r % 11) * 11;
    int xo2 = 0, po2 = 0;
    const bool has2 = (i2 < 726);
    if (has2) { l = i2 / 121; r = i2 % 121; xo2 = l * 121 + (r / 11) * 11; po2 = l * 121 + (r % 11) * 11; }

    for (int i = 0; i < 20; ++i) {
        for (int j = tid; j < 726; j += 256) {
            xi[j] = X2g[i * 726 + j];
            pp[j] = P2g[(i * 40 + o) * 726 + j];
        }
        __syncthreads();
        #pragma unroll
        for (int k = 0; k < 11; ++k) {
            float2 u = xi[xo0 + k], v = pp[po0 + k];
            a0.x += u.x * v.x + u.y * v.y; a0.y += u.y * v.x - u.x * v.y;
        }
        #pragma unroll
        for (int k = 0; k < 11; ++k) {
            float2 u = xi[xo1 + k], v = pp[po1 + k];
            a1.x += u.x * v.x + u.y * v.y; a1.y += u.y * v.x - u.x * v.y;
        }
        if (has2) {
            #pragma unroll
            for (int k = 0; k < 11; ++k) {
                float2 u = xi[xo2 + k], v = pp[po2 + k];
                a2.x += u.x * v.x + u.y * v.y; a2.y += u.y * v.x - u.x * v.y;
            }
        }
        __syncthreads();
    }
    z2[i0] = a0;
    z2[i1] = a1;
    if (has2) z2[i2] = a2;
    __syncthreads();
    // fh2[k2,m,n] = sum_l W_INV2[k2,l,m,n]*z2[l,m,n]
    for (int i = tid; i < 1452; i += 256) {
        int k2 = i / 121, rr = i % 121;
        float2 s = {0.f, 0.f};
        #pragma unroll
        for (int ll = 0; ll < 6; ++ll) {
            float w = WI2[k2 * 726 + ll * 121 + rr];
            float2 z = z2[ll * 121 + rr];
            s.x += w * z.x; s.y += w * z.y;
        }
        fh2[i] = s;
    }
    __syncthreads();
    // t2[k2,m,g] = sum_n fh2[k2,m,n]*E_A2[n,g]
    for (int i = tid; i < 1584; i += 256) {
        int k2 = i / 132, rr = i % 132, m = rr / 12, g = rr % 12;
        float2 s = {0.f, 0.f};
        #pragma unroll
        for (int n = 0; n < 11; ++n) {
            float2 f = fh2[k2 * 121 + m * 11 + n], e = EA2[n * 12 + g];
            s.x += f.x * e.x - f.y * e.y;
            s.y += f.x * e.y + f.y * e.x;
        }
        t2[i] = s;
    }
    __syncthreads();
    // partial = sum over (k2,a,g) of W_INT[k2]*relu(Re sum_m E_A2[m,a]*t2[k2,m,g])
    float partial = 0.f;
    for (int i = tid; i < 1728; i += 256) {
        int k2 = i / 144, rr = i % 144, a = rr / 12, g = rr % 12;
        float s = 0.f;
        #pragma unroll
        for (int m = 0; m < 11; ++m) {
            float2 e = EA2[m * 12 + a], t = t2[(k2 * 11 + m) * 12 + g];
            s += e.x * t.x - e.y * t.y;
        }
        if (s > 0.f) partial += WIT[k2] * s;
    }
    for (int off = 32; off > 0; off >>= 1) partial += __shfl_down(partial, off, 64);
    if ((tid & 63) == 0) red[tid >> 6] = partial;
    __syncthreads();
    if (tid == 0) featg[b * 40 + o] = (red[0] + red[1] + red[2] + red[3]) * (1.0f / 144.0f);
}

// ---------------------------------------------------------------------------
// out[b,f] = sum_o feat[b,o]*w_lin[f,o] + b_lin[f]
// ---------------------------------------------------------------------------
__global__ __launch_bounds__(256) void final_kernel(const float* __restrict__ ws,
                                                    const float* __restrict__ wl,
                                                    const float* __restrict__ bl,
                                                    float* __restrict__ out) {
    int idx = blockIdx.x * 256 + threadIdx.x;
    if (idx >= 1280) return;
    int b = idx / 10, f = idx % 10;
    const float* feat = ws + OFF_FEAT;
    float s = bl[f];
    for (int o = 0; o < 40; ++o) s += feat[b * 40 + o] * wl[f * 40 + o];
    out[idx] = s;
}

// ---------------------------------------------------------------------------
extern "C" void kernel_launch(void* const* d_in, const int* in_sizes, int n_in,
                              void* d_out, int out_size, void* d_ws, size_t ws_size,
                              hipStream_t stream) {
    (void)in_sizes; (void)n_in; (void)out_size; (void)ws_size;
    const float* x  = (const float*)d_in[0];
    const float* k1 = (const float*)d_in[1];
    const float* k2 = (const float*)d_in[2];
    const float* wl = (const float*)d_in[3];
    const float* bl = (const float*)d_in[4];
    float* out = (float*)d_out;
    float* ws  = (float*)d_ws;

    build_tables_kernel<<<827, 256, 0, stream>>>(ws);           // 211550 elems
    psi1_kernel<<<15, 256, 0, stream>>>(ws, k1);                // 3800
    xform1_kernel<<<128, 256, 0, stream>>>(ws, x);              // per-batch
    psi2_kernel<<<2269, 256, 0, stream>>>(ws, k2);              // 580800
    stage1_kernel<<<128 * 20, 256, 0, stream>>>(ws);
    stage2_kernel<<<128 * 40, 256, 0, stream>>>(ws);
    final_kernel<<<5, 256, 0, stream>>>(ws, wl, bl, out);
}